// Round 8
// baseline (3642.278 us; speedup 1.0000x reference)
//
#include <hip/hip_runtime.h>
#include <math.h>

// TopK router: logits = x @ W^T + b ; top-2 over E=64 ; sparse softmax.
// x: [T=16384, D=2048] f32, W: [64, 2048] f32, b: [64] f32.
// d_out: [T*64] router probs f32, then [T*2] top-k indices as f32.
//
// R8: 2-D lane split. lane = (g,tok) = 4 k-quad-groups x 16 tokens.
// TB=16 -> grid=1024 -> 4 blocks/CU (R7 died at grid=256 = 1 block/CU).
// Wave covers 16 experts (4 waves = 64). Thread caches its 8 x-quads
// (32 floats) in regs per chunk, reuses across 16 experts; W float4 loads
// are 1-line wave-instrs (4 g-quads contiguous 64B, 16-tok broadcast).
// x via LDS ds_read_b128, ROWP=132 -> canonical uniform bank spread.
// f32 chains of 8 float4-slots per 32-k + f64 accumulate (R5-proven);
// k-groups combined with 2 f64 shfl_xor steps. No runtime-indexed
// register arrays (rule #20); no inline asm; no lambdas.
// Spill sentinel: WRITE_SIZE must stay ~4.2 MB.

#define RD 2048
#define RE 64
#define TPB 16                  // tokens per block
#define CK 128                  // k-floats per chunk
#define NCH (RD / CK)           // 16 chunks
#define ROWP 132                // padded LDS row (dwords)
#define NWV 4                   // waves per block
#define EPW 16                  // experts per wave

// one chunk-step of the per-expert chain: quad m
#define STEP(M, XQ) do {                                                   \
    const float4 w_ = *(const float4*)(wr_ + (M) * 16);                    \
    a_.x = fmaf((XQ).x, w_.x, a_.x); a_.y = fmaf((XQ).y, w_.y, a_.y);      \
    a_.z = fmaf((XQ).z, w_.z, a_.z); a_.w = fmaf((XQ).w, w_.w, a_.w);      \
} while (0)

__global__ __launch_bounds__(256, 4) void topk_router_kernel(
    const float* __restrict__ x,
    const float* __restrict__ W,
    const float* __restrict__ b,
    float* __restrict__ out_router,
    float* __restrict__ out_idx,
    int total_tokens)
{
    const int tid  = threadIdx.x;
    const int lane = tid & 63;
    const int wv   = __builtin_amdgcn_readfirstlane(tid >> 6);  // 0..3
    const int g    = lane >> 4;      // k-quad group 0..3
    const int tok  = lane & 15;      // token within tile
    const int tok0 = blockIdx.x * TPB;

    __shared__ __align__(16) float  xs[2][TPB * ROWP];   // 16.9 KB
    __shared__ __align__(16) double lg[TPB][RE + 1];     // 8.3 KB

    // staging map: thread -> (token row, 32B segment), coalesced global reads
    const int stok = tid >> 4;       // 0..15
    const int sseg = tid & 15;       // 0..15
    const int tmax = total_tokens - 1;
    const float* gsrc = x + (size_t)min(tok0 + stok, tmax) * RD + sseg * 8;
    float* ld0 = &xs[0][stok * ROWP + sseg * 8];
    float* ld1 = &xs[1][stok * ROWP + sseg * 8];

    const int e0 = wv * EPW;
    const float* wbase = W + (size_t)e0 * RD + g * 4;    // per-lane +16B*g

    double dacc[EPW];
#pragma unroll
    for (int e = 0; e < EPW; ++e) dacc[e] = 0.0;

    // prologue: stage chunk 0 -> buf 0
    {
        const float4 a0 = *(const float4*)(gsrc);
        const float4 a1 = *(const float4*)(gsrc + 4);
        *(float4*)(ld0)     = a0;
        *(float4*)(ld0 + 4) = a1;
    }
    __syncthreads();

#pragma unroll 1
    for (int c = 0; c < NCH; ++c) {
        // issue next chunk's global loads early (write-late after barrier)
        float4 na, nb;
        const bool more = (c + 1 < NCH);
        if (more) {
            na = *(const float4*)(gsrc + (size_t)(c + 1) * CK);
            nb = *(const float4*)(gsrc + (size_t)(c + 1) * CK + 4);
        }

        // x quads -> 8 named float4 regs (reused across 16 experts)
        const float* xb = &xs[c & 1][tok * ROWP + g * 4];
        const float4 xq0 = *(const float4*)(xb + 0 * 16);
        const float4 xq1 = *(const float4*)(xb + 1 * 16);
        const float4 xq2 = *(const float4*)(xb + 2 * 16);
        const float4 xq3 = *(const float4*)(xb + 3 * 16);
        const float4 xq4 = *(const float4*)(xb + 4 * 16);
        const float4 xq5 = *(const float4*)(xb + 5 * 16);
        const float4 xq6 = *(const float4*)(xb + 6 * 16);
        const float4 xq7 = *(const float4*)(xb + 7 * 16);

        const float* wc = wbase + (size_t)c * CK;
#pragma unroll
        for (int e = 0; e < EPW; ++e) {
            const float* wr_ = wc + (size_t)e * RD;
            float4 a_;
            {
                const float4 w_ = *(const float4*)(wr_);
                a_.x = xq0.x * w_.x; a_.y = xq0.y * w_.y;
                a_.z = xq0.z * w_.z; a_.w = xq0.w * w_.w;
            }
            STEP(1, xq1); STEP(2, xq2); STEP(3, xq3);
            STEP(4, xq4); STEP(5, xq5); STEP(6, xq6); STEP(7, xq7);
            dacc[e] += (double)((a_.x + a_.y) + (a_.z + a_.w));
        }

        __syncthreads();
        if (more) {
            float* ldn = ((c + 1) & 1) ? ld1 : ld0;
            *(float4*)(ldn)     = na;
            *(float4*)(ldn + 4) = nb;
        }
        __syncthreads();
    }

    // ---- combine the 4 k-groups (f64 butterfly), exchange via LDS ----
#pragma unroll
    for (int e = 0; e < EPW; ++e) {
        dacc[e] += __shfl_xor(dacc[e], 16, 64);
        dacc[e] += __shfl_xor(dacc[e], 32, 64);
    }
    // lane's g-quarter writes experts e0 + [g*4, g*4+4)  (static dacc index)
#pragma unroll
    for (int e = 0; e < EPW; ++e) {
        if ((e >> 2) == g) lg[tok][e0 + e] = dacc[e];
    }
    __syncthreads();

    const double bias = (double)b[lane];

    // epilogue: wave wv handles tokens [wv*4, wv*4+4); lane = expert
#pragma unroll 1
    for (int tt = 0; tt < TPB / NWV; ++tt) {
        const int t = wv * (TPB / NWV) + tt;
        const int token = tok0 + t;
        const double v = lg[t][lane] + bias;

        // argmax #1 (value desc, tie -> lower lane)
        double bestv = v;
        int besti = lane;
#pragma unroll
        for (int off = 32; off > 0; off >>= 1) {
            double ov = __shfl_xor(bestv, off, 64);
            int oi = __shfl_xor(besti, off, 64);
            if (ov > bestv || (ov == bestv && oi < besti)) { bestv = ov; besti = oi; }
        }

        // argmax #2 excluding winner
        double v2 = (lane == besti) ? -INFINITY : v;
        double best2v = v2;
        int best2i = lane;
#pragma unroll
        for (int off = 32; off > 0; off >>= 1) {
            double ov = __shfl_xor(best2v, off, 64);
            int oi = __shfl_xor(best2i, off, 64);
            if (ov > best2v || (ov == best2v && oi < best2i)) { best2v = ov; best2i = oi; }
        }

        // 2-element softmax; all other experts exactly 0
        const float e2 = expf((float)(best2v - bestv));
        const float denom = 1.0f + e2;
        const float p1v = 1.0f / denom;
        const float p2v = e2 / denom;

        if (token < total_tokens) {
            float outv = 0.0f;
            if (lane == besti) outv = p1v;
            else if (lane == best2i) outv = p2v;
            out_router[(size_t)token * RE + lane] = outv;
            if (lane == 0) {
                out_idx[(size_t)token * 2 + 0] = (float)besti;
                out_idx[(size_t)token * 2 + 1] = (float)best2i;
            }
        }
    }
}

extern "C" void kernel_launch(void* const* d_in, const int* in_sizes, int n_in,
                              void* d_out, int out_size, void* d_ws, size_t ws_size,
                              hipStream_t stream) {
    const float* x = (const float*)d_in[0];
    const float* W = (const float*)d_in[1];
    const float* b = (const float*)d_in[2];

    const int E = in_sizes[2];                 // 64
    const int D = in_sizes[1] / E;             // 2048
    const int T = in_sizes[0] / D;             // 16384
    (void)E; (void)D;

    float* out_router = (float*)d_out;
    float* out_idx = out_router + (size_t)T * RE;

    const int grid = (T + TPB - 1) / TPB;      // 1024

    topk_router_kernel<<<grid, 256, 0, stream>>>(x, W, b, out_router, out_idx, T);
}

// Round 9
// 279.570 us; speedup vs baseline: 13.0281x; 13.0281x over previous
//
#include <hip/hip_runtime.h>
#include <math.h>

// TopK router: logits = x @ W^T + b ; top-2 over E=64 ; sparse softmax.
// x: [T=16384, D=2048] f32, W: [64, 2048] f32, b: [64] f32.
// d_out: [T*64] router probs f32, then [T*2] top-k indices as f32.
//
// R9: two kernels.
//  A) transpose W[64][2048] -> WT[2048][64] in d_ws (512 KB, LDS-tiled).
//  B) R5 geometry (4-wave K-split, 16 tok/block, lane=expert, grid 1024)
//     with BOTH operand paths fixed:
//     - W from WT: per k one coalesced global_load_dword (1 line/instr,
//       16 fmas/instr) -- kills R5's 64-line-scatter (~55 us of L1 traffic).
//     - x via uniform-address global_load_dwordx4 broadcasts on the VMEM
//       pipe (each quad read exactly once per wave; K-split => no reuse to
//       stage). No LDS, no barriers in the main loop. The x base pointer is
//       laundered through an opaque v_mov so the compiler cannot route it
//       to s_load (R2/R7 scalar-cache disease).
//     Summation order identical to R5 (indices exact in R1-R8): 32-k
//     s-blocks, fp32 fma chains over 8 float4-slots, f64 accumulate.
// Spill sentinel: WRITE_SIZE must stay ~4.7 MB (4.2 out + 0.5 WT).

#define RD 2048
#define RE 64
#define NW 4                    // waves per block (K-split)
#define TPB 16                  // tokens per block
#define DQ (RD / NW)            // 512 k per wave
#define NSB (DQ / 32)           // 16 s-blocks of 32 k

// ---------- kernel A: W -> WT ----------
__global__ __launch_bounds__(256) void wt_kernel(
    const float* __restrict__ W, float* __restrict__ WT)
{
    __shared__ float tile[64][65];
    const int k0 = blockIdx.x * 64;
    const int r = threadIdx.x >> 6;     // 0..3
    const int c = threadIdx.x & 63;     // 0..63
#pragma unroll
    for (int i = 0; i < 16; ++i) {
        const int e = r + i * 4;
        tile[e][c] = W[(size_t)e * RD + k0 + c];     // coalesced in c=k
    }
    __syncthreads();
#pragma unroll
    for (int i = 0; i < 16; ++i) {
        const int k = r + i * 4;
        WT[(size_t)(k0 + k) * RE + c] = tile[c][k];  // coalesced in c=e
    }
}

// one quad-step of the per-token chain
#define STEP(W4, XQ) do {                                                  \
    a_.x = fmaf((XQ).x, (W4).x, a_.x); a_.y = fmaf((XQ).y, (W4).y, a_.y);  \
    a_.z = fmaf((XQ).z, (W4).z, a_.z); a_.w = fmaf((XQ).w, (W4).w, a_.w);  \
} while (0)

// ---------- kernel B: GEMM + top-2 + sparse softmax ----------
__global__ __launch_bounds__(256, 3) void topk_router_kernel(
    const float* __restrict__ x,
    const float* __restrict__ WT,
    const float* __restrict__ b,
    float* __restrict__ out_router,
    float* __restrict__ out_idx,
    int total_tokens)
{
    const int lane = threadIdx.x & 63;                                   // expert
    const int wq = __builtin_amdgcn_readfirstlane((int)(threadIdx.x >> 6)); // K-quarter
    const int tok0 = blockIdx.x * TPB;

    __shared__ double lg[NW][TPB][RE + 2];   // 33.8 KB -> 4 blocks/CU

    // launder: opaque zero in a VGPR so x addressing stays on the vector
    // path (uniform-address global_load broadcasts, NOT s_load).
    int vzero;
    asm volatile("v_mov_b32 %0, 0" : "=v"(vzero));

    const int tmax = total_tokens - 1;
    const float* xb  = x + (size_t)wq * DQ + vzero;          // + token*RD later
    const float* wtb = WT + (size_t)wq * DQ * RE + lane;     // coalesced col

    double dacc[TPB];
#pragma unroll
    for (int t = 0; t < TPB; ++t) dacc[t] = 0.0;

#pragma unroll 1
    for (int sb = 0; sb < NSB; ++sb) {
        // W column slice for these 32 ks: 32 coalesced b32 loads,
        // packed into 8 float4 quad-slots (register naming only).
        const float* wk = wtb + (size_t)sb * 32 * RE;
        float4 w0_, w1_, w2_, w3_, w4_, w5_, w6_, w7_;
#define LDW(Q, DST)                                                        \
        DST.x = wk[(4 * (Q) + 0) * RE]; DST.y = wk[(4 * (Q) + 1) * RE];    \
        DST.z = wk[(4 * (Q) + 2) * RE]; DST.w = wk[(4 * (Q) + 3) * RE];
        LDW(0, w0_) LDW(1, w1_) LDW(2, w2_) LDW(3, w3_)
        LDW(4, w4_) LDW(5, w5_) LDW(6, w6_) LDW(7, w7_)
#undef LDW

        const int koff = sb * 32;
#pragma unroll
        for (int tt = 0; tt < TPB; ++tt) {
            const int trow = min(tok0 + tt, tmax);
            const float4* xp = (const float4*)(xb + (size_t)trow * RD + koff);
            const float4 xq0 = xp[0], xq1 = xp[1], xq2 = xp[2], xq3 = xp[3];
            const float4 xq4 = xp[4], xq5 = xp[5], xq6 = xp[6], xq7 = xp[7];
            float4 a_;
            a_.x = xq0.x * w0_.x; a_.y = xq0.y * w0_.y;
            a_.z = xq0.z * w0_.z; a_.w = xq0.w * w0_.w;
            STEP(w1_, xq1); STEP(w2_, xq2); STEP(w3_, xq3);
            STEP(w4_, xq4); STEP(w5_, xq5); STEP(w6_, xq6); STEP(w7_, xq7);
            dacc[tt] += (double)((a_.x + a_.y) + (a_.z + a_.w));
        }
    }

    // ---- combine K-quarters via f64 partials in LDS (R5-proven) ----
#pragma unroll
    for (int t = 0; t < TPB; ++t) lg[wq][t][lane] = dacc[t];
    __syncthreads();

    const double bias = (double)b[lane];

    // epilogue: wave wq owns tokens [wq*4, wq*4+4)
#pragma unroll 1
    for (int tt = 0; tt < TPB / NW; ++tt) {
        const int t = wq * (TPB / NW) + tt;
        const int token = tok0 + t;
        const double v = lg[0][t][lane] + lg[1][t][lane]
                       + lg[2][t][lane] + lg[3][t][lane] + bias;

        // argmax #1 (value desc, tie -> lower lane)
        double bestv = v;
        int besti = lane;
#pragma unroll
        for (int off = 32; off > 0; off >>= 1) {
            double ov = __shfl_xor(bestv, off, 64);
            int oi = __shfl_xor(besti, off, 64);
            if (ov > bestv || (ov == bestv && oi < besti)) { bestv = ov; besti = oi; }
        }

        // argmax #2 excluding winner
        double v2 = (lane == besti) ? -INFINITY : v;
        double best2v = v2;
        int best2i = lane;
#pragma unroll
        for (int off = 32; off > 0; off >>= 1) {
            double ov = __shfl_xor(best2v, off, 64);
            int oi = __shfl_xor(best2i, off, 64);
            if (ov > best2v || (ov == best2v && oi < best2i)) { best2v = ov; best2i = oi; }
        }

        // 2-element softmax; all other experts exactly 0
        const float e2 = expf((float)(best2v - bestv));
        const float denom = 1.0f + e2;
        const float p1v = 1.0f / denom;
        const float p2v = e2 / denom;

        if (token < total_tokens) {
            float outv = 0.0f;
            if (lane == besti) outv = p1v;
            else if (lane == best2i) outv = p2v;
            out_router[(size_t)token * RE + lane] = outv;
            if (lane == 0) {
                out_idx[(size_t)token * 2 + 0] = (float)besti;
                out_idx[(size_t)token * 2 + 1] = (float)best2i;
            }
        }
    }
}

extern "C" void kernel_launch(void* const* d_in, const int* in_sizes, int n_in,
                              void* d_out, int out_size, void* d_ws, size_t ws_size,
                              hipStream_t stream) {
    const float* x = (const float*)d_in[0];
    const float* W = (const float*)d_in[1];
    const float* b = (const float*)d_in[2];

    const int E = in_sizes[2];                 // 64
    const int D = in_sizes[1] / E;             // 2048
    const int T = in_sizes[0] / D;             // 16384
    (void)E; (void)D;

    float* WT = (float*)d_ws;                  // 2048*64*4 = 512 KB
    float* out_router = (float*)d_out;
    float* out_idx = out_router + (size_t)T * RE;

    wt_kernel<<<RD / 64, 256, 0, stream>>>(W, WT);

    const int grid = (T + TPB - 1) / TPB;      // 1024
    topk_router_kernel<<<grid, 256, 0, stream>>>(x, WT, b, out_router, out_idx, T);
}

// Round 10
// 88.712 us; speedup vs baseline: 41.0572x; 3.1514x over previous
//
#include <hip/hip_runtime.h>
#include <math.h>

// TopK router via MFMA: logits = x @ W^T + b ; top-2 over E=64 ; sparse softmax.
// x: [T=16384, D=2048] f32, W: [64, 2048] f32, b: [64] f32.
// d_out: [T*64] router probs f32, then [T*2] top-k indices as f32.
//
// R10: fp32 GEMM emulated with 6 bf16 MFMA products (3-way split per
// operand: v = vh + vl + vl2; keep (h,h),(h,l),(l,h),(l,l),(h,l2),(l2,h)).
// Dropped terms ~2^-27 -> ~3e-8 logit error; fp32 MFMA accumulation with
// f64 partial merge every 8 chunks -> ~6e-7 total (same order as R5's
// verified chains -> indices match numpy). R5-R9 showed all VALU paths hit
// a ~50-70 us operand-broadcast floor (16B/instr to 64 lanes on any pipe);
// MFMA shares operands inside the matrix unit.
//  - Prep kernel: W[64][2048] -> WB fragments in d_ws (768 KB): for each
//    (kstep, etile, comp): lane-major 16B frags = coalesced 1KB loads.
//  - Main: block = 32 tokens, 4 waves = (2 toktiles x 2 ehalves); per chunk
//    (64 k): stage x -> 3-way bf16 -> LDS in A-frag layout (dbuf, one
//    syncthreads per chunk); 24 MFMAs per wave per chunk.
//  - Frag convention (A and B identical, cancels any common k-permutation):
//    lane&15 = m/n, lane>>4 = k-group, 8 contiguous k per lane.
//    C/D: col(expert) = lane&15, row(token) = (lane>>4)*4 + reg  [m89].
// Epilogue: logits (f64) through LDS, R5-verified butterfly top-2.
// Spill sentinel: WRITE_SIZE ~5.0 MB.

#define RD 2048
#define RE 64
#define TB 32                    // tokens per block
#define NCH 32                   // chunks of 64 k

typedef __attribute__((ext_vector_type(8))) short bf16x8;
typedef __attribute__((ext_vector_type(4))) float f32x4;
typedef __attribute__((ext_vector_type(4))) unsigned int u32x4;

__device__ __forceinline__ unsigned short f2b(float f) {  // RNE f32->bf16 bits
    unsigned int u = __float_as_uint(f);
    unsigned int r = ((u >> 16) & 1u) + 0x7fffu;
    return (unsigned short)((u + r) >> 16);
}
__device__ __forceinline__ float b2f(unsigned short h) {
    return __uint_as_float(((unsigned int)h) << 16);
}

// split 8 floats -> packed bf16 h/l/l2 (4 dwords each)
__device__ __forceinline__ void cvt8(const f32x4 a, const f32x4 bq,
                                     unsigned int* h, unsigned int* l,
                                     unsigned int* l2) {
    float v[8] = {a.x, a.y, a.z, a.w, bq.x, bq.y, bq.z, bq.w};
#pragma unroll
    for (int j = 0; j < 4; ++j) {
        const float a0 = v[2 * j], a1 = v[2 * j + 1];
        const unsigned short h0 = f2b(a0); const float r0 = a0 - b2f(h0);
        const unsigned short h1 = f2b(a1); const float r1 = a1 - b2f(h1);
        const unsigned short m0 = f2b(r0); const float s0 = r0 - b2f(m0);
        const unsigned short m1 = f2b(r1); const float s1 = r1 - b2f(m1);
        const unsigned short q0 = f2b(s0);
        const unsigned short q1 = f2b(s1);
        h[j]  = (unsigned int)h0 | ((unsigned int)h1 << 16);
        l[j]  = (unsigned int)m0 | ((unsigned int)m1 << 16);
        l2[j] = (unsigned int)q0 | ((unsigned int)q1 << 16);
    }
}

// ---------- prep: W -> 3-way bf16 B-fragments ----------
// WB dword layout: ((ks*4 + et)*3 + comp)*256 + lane*4   (64 ks total)
__global__ __launch_bounds__(256) void wprep_kernel(
    const float* __restrict__ W, unsigned int* __restrict__ WB)
{
    const int ks = blockIdx.x;            // 0..63
    const int et = threadIdx.x >> 6;      // 0..3
    const int lane = threadIdx.x & 63;
    const int e = et * 16 + (lane & 15);
    const int k0 = ks * 32 + (lane >> 4) * 8;
    const float* src = W + (size_t)e * RD + k0;
    const f32x4 a = *(const f32x4*)(src);
    const f32x4 bq = *(const f32x4*)(src + 4);
    unsigned int h[4], l[4], l2[4];
    cvt8(a, bq, h, l, l2);
    unsigned int* dst = WB + (size_t)((ks * 4 + et) * 3) * 256 + lane * 4;
    *(u32x4*)(dst)       = *(u32x4*)h;
    *(u32x4*)(dst + 256) = *(u32x4*)l;
    *(u32x4*)(dst + 512) = *(u32x4*)l2;
}

// ---------- main ----------
__global__ __launch_bounds__(256, 4) void topk_router_kernel(
    const float* __restrict__ x,
    const unsigned int* __restrict__ WB,
    const float* __restrict__ b,
    float* __restrict__ out_router,
    float* __restrict__ out_idx,
    int total_tokens)
{
    const int tid = threadIdx.x;
    const int lane = tid & 63;
    const int wv = __builtin_amdgcn_readfirstlane(tid >> 6);  // 0..3
    const int toktile = wv >> 1;          // 0..1
    const int ehalf = wv & 1;             // 0..1
    const int tok0 = blockIdx.x * TB;

    // XA[buf][toktile][ks][comp][fraglane*4 dwords] : 24 KB
    __shared__ __align__(16) unsigned int XA[2][2][2][3][256];

    // staging map: tok = tid>>3 (0..31), part = tid&7 (8 consecutive floats)
    const int stok = tid >> 3;
    const int part = tid & 7;
    const int tmax = total_tokens - 1;
    const float* gsrc = x + (size_t)min(tok0 + stok, tmax) * RD + part * 8;
    const int s_tt = stok >> 4;
    const int s_ks = part >> 2;                       // kstep within chunk
    const int s_fl = (part & 3) * 16 + (stok & 15);   // frag lane

    f32x4 acc[2];
    double acc64[2][4];
#pragma unroll
    for (int ei = 0; ei < 2; ++ei) {
        acc[ei] = (f32x4){0.f, 0.f, 0.f, 0.f};
        acc64[ei][0] = 0.0; acc64[ei][1] = 0.0;
        acc64[ei][2] = 0.0; acc64[ei][3] = 0.0;
    }

    // prologue: stage chunk 0
    {
        const f32x4 a = *(const f32x4*)(gsrc);
        const f32x4 bq = *(const f32x4*)(gsrc + 4);
        unsigned int h[4], l[4], l2[4];
        cvt8(a, bq, h, l, l2);
        *(u32x4*)&XA[0][s_tt][s_ks][0][s_fl * 4] = *(u32x4*)h;
        *(u32x4*)&XA[0][s_tt][s_ks][1][s_fl * 4] = *(u32x4*)l;
        *(u32x4*)&XA[0][s_tt][s_ks][2][s_fl * 4] = *(u32x4*)l2;
    }
    __syncthreads();

#pragma unroll 1
    for (int c = 0; c < NCH; ++c) {
        const int buf = c & 1;
        // issue next chunk's global loads early (T14)
        f32x4 na = {0.f, 0.f, 0.f, 0.f}, nb = {0.f, 0.f, 0.f, 0.f};
        if (c + 1 < NCH) {
            na = *(const f32x4*)(gsrc + (size_t)(c + 1) * 64);
            nb = *(const f32x4*)(gsrc + (size_t)(c + 1) * 64 + 4);
        }

        // compute chunk c: 2 ksteps x 2 etiles x 6 products
#pragma unroll
        for (int ks = 0; ks < 2; ++ks) {
            const bf16x8 Ah  = *(const bf16x8*)&XA[buf][toktile][ks][0][lane * 4];
            const bf16x8 Al  = *(const bf16x8*)&XA[buf][toktile][ks][1][lane * 4];
            const bf16x8 Al2 = *(const bf16x8*)&XA[buf][toktile][ks][2][lane * 4];
            const int ksg = c * 2 + ks;
#pragma unroll
            for (int ei = 0; ei < 2; ++ei) {
                const int et = ehalf * 2 + ei;
                const unsigned int* wp =
                    WB + (size_t)((ksg * 4 + et) * 3) * 256 + lane * 4;
                const bf16x8 Bh  = *(const bf16x8*)(wp);
                const bf16x8 Bl  = *(const bf16x8*)(wp + 256);
                const bf16x8 Bl2 = *(const bf16x8*)(wp + 512);
                f32x4 a = acc[ei];
                a = __builtin_amdgcn_mfma_f32_16x16x32_bf16(Ah,  Bh,  a, 0, 0, 0);
                a = __builtin_amdgcn_mfma_f32_16x16x32_bf16(Ah,  Bl,  a, 0, 0, 0);
                a = __builtin_amdgcn_mfma_f32_16x16x32_bf16(Al,  Bh,  a, 0, 0, 0);
                a = __builtin_amdgcn_mfma_f32_16x16x32_bf16(Al,  Bl,  a, 0, 0, 0);
                a = __builtin_amdgcn_mfma_f32_16x16x32_bf16(Ah,  Bl2, a, 0, 0, 0);
                a = __builtin_amdgcn_mfma_f32_16x16x32_bf16(Al2, Bh,  a, 0, 0, 0);
                acc[ei] = a;
            }
        }

        // f64 partial merge every 8 chunks (limits fp32 accum chains to 96)
        if ((c & 7) == 7) {
#pragma unroll
            for (int ei = 0; ei < 2; ++ei) {
                acc64[ei][0] += (double)acc[ei].x;
                acc64[ei][1] += (double)acc[ei].y;
                acc64[ei][2] += (double)acc[ei].z;
                acc64[ei][3] += (double)acc[ei].w;
                acc[ei] = (f32x4){0.f, 0.f, 0.f, 0.f};
            }
        }

        // convert + write next chunk into the other buffer, one barrier
        if (c + 1 < NCH) {
            unsigned int h[4], l[4], l2[4];
            cvt8(na, nb, h, l, l2);
            const int nbuf = (c + 1) & 1;
            *(u32x4*)&XA[nbuf][s_tt][s_ks][0][s_fl * 4] = *(u32x4*)h;
            *(u32x4*)&XA[nbuf][s_tt][s_ks][1][s_fl * 4] = *(u32x4*)l;
            *(u32x4*)&XA[nbuf][s_tt][s_ks][2][s_fl * 4] = *(u32x4*)l2;
        }
        __syncthreads();
    }

    // ---- exchange logits (f64) through LDS (aliases XA, 16 KB <= 24 KB) ----
    double* lg = (double*)&XA[0][0][0][0][0];
#pragma unroll
    for (int ei = 0; ei < 2; ++ei) {
#pragma unroll
        for (int r = 0; r < 4; ++r) {
            const int t = toktile * 16 + (lane >> 4) * 4 + r;     // C/D row
            const int e = (ehalf * 2 + ei) * 16 + (lane & 15);    // C/D col
            lg[(size_t)t * RE + e] = acc64[ei][r];
        }
    }
    __syncthreads();

    const double bias = (double)b[lane];

    // epilogue (R5-verified): wave wv handles tokens [wv*8, wv*8+8)
#pragma unroll 1
    for (int tt = 0; tt < TB / 4; ++tt) {
        const int t = wv * (TB / 4) + tt;
        const int token = tok0 + t;
        const double v = lg[(size_t)t * RE + lane] + bias;

        // argmax #1 (value desc, tie -> lower lane)
        double bestv = v;
        int besti = lane;
#pragma unroll
        for (int off = 32; off > 0; off >>= 1) {
            double ov = __shfl_xor(bestv, off, 64);
            int oi = __shfl_xor(besti, off, 64);
            if (ov > bestv || (ov == bestv && oi < besti)) { bestv = ov; besti = oi; }
        }

        // argmax #2 excluding winner
        double v2 = (lane == besti) ? -INFINITY : v;
        double best2v = v2;
        int best2i = lane;
#pragma unroll
        for (int off = 32; off > 0; off >>= 1) {
            double ov = __shfl_xor(best2v, off, 64);
            int oi = __shfl_xor(best2i, off, 64);
            if (ov > best2v || (ov == best2v && oi < best2i)) { best2v = ov; best2i = oi; }
        }

        // 2-element softmax; all other experts exactly 0
        const float e2 = expf((float)(best2v - bestv));
        const float denom = 1.0f + e2;
        const float p1v = 1.0f / denom;
        const float p2v = e2 / denom;

        if (token < total_tokens) {
            float outv = 0.0f;
            if (lane == besti) outv = p1v;
            else if (lane == best2i) outv = p2v;
            out_router[(size_t)token * RE + lane] = outv;
            if (lane == 0) {
                out_idx[(size_t)token * 2 + 0] = (float)besti;
                out_idx[(size_t)token * 2 + 1] = (float)best2i;
            }
        }
    }
}

extern "C" void kernel_launch(void* const* d_in, const int* in_sizes, int n_in,
                              void* d_out, int out_size, void* d_ws, size_t ws_size,
                              hipStream_t stream) {
    const float* x = (const float*)d_in[0];
    const float* W = (const float*)d_in[1];
    const float* b = (const float*)d_in[2];

    const int E = in_sizes[2];                 // 64
    const int D = in_sizes[1] / E;             // 2048
    const int T = in_sizes[0] / D;             // 16384
    (void)E; (void)D;

    unsigned int* WB = (unsigned int*)d_ws;    // 64*4*3*1024 B = 768 KB
    float* out_router = (float*)d_out;
    float* out_idx = out_router + (size_t)T * RE;

    wprep_kernel<<<64, 256, 0, stream>>>(W, WB);

    const int grid = (T + TB - 1) / TB;        // 512
    topk_router_kernel<<<grid, 256, 0, stream>>>(x, WB, b, out_router, out_idx, T);
}

// Round 11
// 65.601 us; speedup vs baseline: 55.5221x; 1.3523x over previous
//
#include <hip/hip_runtime.h>
#include <math.h>

// TopK router via MFMA: logits = x @ W^T + b ; top-2 over E=64 ; sparse softmax.
// x: [T=16384, D=2048] f32, W: [64, 2048] f32, b: [64] f32.
// d_out: [T*64] router probs f32, then [T*2] top-k indices as f32.
//
// R11 = R10 (88.7 us, absmax 0.0) + three fixes:
//  1) XOR bank-quad swizzle off(f) = 4f ^ 4*((f>>3)&7) on BOTH LDS staging
//     writes and fragment reads (same involution) -- kills R10's 8-way
//     ds_write conflict (SQ_LDS_BANK_CONFLICT 1.1e7 ~ 18 us of LDS-pipe).
//  2) 512-thread blocks (8 waves = 2 toktiles x 4 etiles), grid 512 ->
//     2 blocks/CU -> 16 waves/CU (R10: 8 waves/CU, 22% occupancy).
//  3) 2-chunk-deep register prefetch (issue c+2 load at top of c; write
//     c+1 late) -- hides L3/HBM latency under ~2 compute phases.
// Numerics bit-identical to R10 (absmax was exactly 0): same 3-way bf16
// split, same 6 products, same fragment k-convention, same f64 merge
// every 8 chunks, same epilogue.
// Spill sentinel: WRITE_SIZE ~5 MB.

#define RD 2048
#define RE 64
#define TB 32                    // tokens per block
#define NCH 32                   // chunks of 64 k

typedef __attribute__((ext_vector_type(8))) short bf16x8;
typedef __attribute__((ext_vector_type(4))) float f32x4;
typedef __attribute__((ext_vector_type(4))) unsigned int u32x4;
typedef __attribute__((ext_vector_type(2))) unsigned int u32x2;

__device__ __forceinline__ unsigned short f2b(float f) {  // RNE f32->bf16 bits
    unsigned int u = __float_as_uint(f);
    unsigned int r = ((u >> 16) & 1u) + 0x7fffu;
    return (unsigned short)((u + r) >> 16);
}
__device__ __forceinline__ float b2f(unsigned short h) {
    return __uint_as_float(((unsigned int)h) << 16);
}

// bank-quad XOR swizzle (dword units); involution, preserves low 2 bits = 0
__device__ __forceinline__ int swz(int f) {
    return (f << 2) ^ (((f >> 3) & 7) << 2);
}

// split 8 floats -> packed bf16 h/l/l2 (4 dwords each) -- wprep only
__device__ __forceinline__ void cvt8(const f32x4 a, const f32x4 bq,
                                     unsigned int* h, unsigned int* l,
                                     unsigned int* l2) {
    float v[8] = {a.x, a.y, a.z, a.w, bq.x, bq.y, bq.z, bq.w};
#pragma unroll
    for (int j = 0; j < 4; ++j) {
        const float a0 = v[2 * j], a1 = v[2 * j + 1];
        const unsigned short h0 = f2b(a0); const float r0 = a0 - b2f(h0);
        const unsigned short h1 = f2b(a1); const float r1 = a1 - b2f(h1);
        const unsigned short m0 = f2b(r0); const float s0 = r0 - b2f(m0);
        const unsigned short m1 = f2b(r1); const float s1 = r1 - b2f(m1);
        const unsigned short q0 = f2b(s0);
        const unsigned short q1 = f2b(s1);
        h[j]  = (unsigned int)h0 | ((unsigned int)h1 << 16);
        l[j]  = (unsigned int)m0 | ((unsigned int)m1 << 16);
        l2[j] = (unsigned int)q0 | ((unsigned int)q1 << 16);
    }
}

// split 4 floats -> packed bf16 h/l/l2 (2 dwords each); same pairing as cvt8
__device__ __forceinline__ void cvt4(const f32x4 a,
                                     unsigned int* h, unsigned int* l,
                                     unsigned int* l2) {
    float v[4] = {a.x, a.y, a.z, a.w};
#pragma unroll
    for (int j = 0; j < 2; ++j) {
        const float a0 = v[2 * j], a1 = v[2 * j + 1];
        const unsigned short h0 = f2b(a0); const float r0 = a0 - b2f(h0);
        const unsigned short h1 = f2b(a1); const float r1 = a1 - b2f(h1);
        const unsigned short m0 = f2b(r0); const float s0 = r0 - b2f(m0);
        const unsigned short m1 = f2b(r1); const float s1 = r1 - b2f(m1);
        const unsigned short q0 = f2b(s0);
        const unsigned short q1 = f2b(s1);
        h[j]  = (unsigned int)h0 | ((unsigned int)h1 << 16);
        l[j]  = (unsigned int)m0 | ((unsigned int)m1 << 16);
        l2[j] = (unsigned int)q0 | ((unsigned int)q1 << 16);
    }
}

// ---------- prep: W -> 3-way bf16 B-fragments (identical to R10) ----------
// WB dword layout: ((ks*4 + et)*3 + comp)*256 + lane*4   (64 ks total)
__global__ __launch_bounds__(256) void wprep_kernel(
    const float* __restrict__ W, unsigned int* __restrict__ WB)
{
    const int ks = blockIdx.x;            // 0..63
    const int et = threadIdx.x >> 6;      // 0..3
    const int lane = threadIdx.x & 63;
    const int e = et * 16 + (lane & 15);
    const int k0 = ks * 32 + (lane >> 4) * 8;
    const float* src = W + (size_t)e * RD + k0;
    const f32x4 a = *(const f32x4*)(src);
    const f32x4 bq = *(const f32x4*)(src + 4);
    unsigned int h[4], l[4], l2[4];
    cvt8(a, bq, h, l, l2);
    unsigned int* dst = WB + (size_t)((ks * 4 + et) * 3) * 256 + lane * 4;
    *(u32x4*)(dst)       = *(u32x4*)h;
    *(u32x4*)(dst + 256) = *(u32x4*)l;
    *(u32x4*)(dst + 512) = *(u32x4*)l2;
}

// ---------- main ----------
__global__ __launch_bounds__(512, 2) void topk_router_kernel(
    const float* __restrict__ x,
    const unsigned int* __restrict__ WB,
    const float* __restrict__ b,
    float* __restrict__ out_router,
    float* __restrict__ out_idx,
    int total_tokens)
{
    const int tid = threadIdx.x;
    const int lane = tid & 63;
    const int wv = __builtin_amdgcn_readfirstlane(tid >> 6);  // 0..7
    const int tt = wv >> 2;               // toktile 0..1
    const int et = wv & 3;                // etile 0..3
    const int tok0 = blockIdx.x * TB;

    // SM[buf][tt][ks][comp][256 dwords] = 24 KB; later aliased as lg[32][66] f64
    __shared__ __align__(16) unsigned int SM[2][2][2][3][256];

    // staging map: thread -> (token, 4 consecutive k); 1 f32x4 per chunk
    const int stok = tid >> 4;            // 0..31
    const int part = tid & 15;            // k-quad 4*part .. 4*part+3
    const int tmax = total_tokens - 1;
    const float* gsrc = x + (size_t)min(tok0 + stok, tmax) * RD + part * 4;
    const int s_tt = stok >> 4;
    const int s_ks = part >> 3;                       // kstep within chunk
    const int s_f  = ((part >> 1) & 3) * 16 + (stok & 15);   // frag lane
    const int s_off = swz(s_f) + (part & 1) * 2;      // swizzled dword offset

    f32x4 acc = {0.f, 0.f, 0.f, 0.f};
    double acc64[4] = {0.0, 0.0, 0.0, 0.0};

    // prologue: stage chunk 0, prefetch chunk 1 into regs
    {
        const f32x4 v0 = *(const f32x4*)(gsrc);
        unsigned int h[2], l[2], l2[2];
        cvt4(v0, h, l, l2);
        *(u32x2*)&SM[0][s_tt][s_ks][0][s_off] = *(u32x2*)h;
        *(u32x2*)&SM[0][s_tt][s_ks][1][s_off] = *(u32x2*)l;
        *(u32x2*)&SM[0][s_tt][s_ks][2][s_off] = *(u32x2*)l2;
    }
    f32x4 pf = *(const f32x4*)(gsrc + 64);
    __syncthreads();

#pragma unroll 1
    for (int c = 0; c < NCH; ++c) {
        const int buf = c & 1;
        // issue chunk c+2's load early (2-deep pipeline)
        const int cn = (c + 2 < NCH) ? (c + 2) : 0;
        const f32x4 nx = *(const f32x4*)(gsrc + (size_t)cn * 64);

        // compute chunk c: 2 ksteps x 6 products (swizzled frag reads)
#pragma unroll
        for (int ks = 0; ks < 2; ++ks) {
            const bf16x8 Ah  = *(const bf16x8*)&SM[buf][tt][ks][0][swz(lane)];
            const bf16x8 Al  = *(const bf16x8*)&SM[buf][tt][ks][1][swz(lane)];
            const bf16x8 Al2 = *(const bf16x8*)&SM[buf][tt][ks][2][swz(lane)];
            const int ksg = c * 2 + ks;
            const unsigned int* wp =
                WB + (size_t)((ksg * 4 + et) * 3) * 256 + lane * 4;
            const bf16x8 Bh  = *(const bf16x8*)(wp);
            const bf16x8 Bl  = *(const bf16x8*)(wp + 256);
            const bf16x8 Bl2 = *(const bf16x8*)(wp + 512);
            acc = __builtin_amdgcn_mfma_f32_16x16x32_bf16(Ah,  Bh,  acc, 0, 0, 0);
            acc = __builtin_amdgcn_mfma_f32_16x16x32_bf16(Ah,  Bl,  acc, 0, 0, 0);
            acc = __builtin_amdgcn_mfma_f32_16x16x32_bf16(Al,  Bh,  acc, 0, 0, 0);
            acc = __builtin_amdgcn_mfma_f32_16x16x32_bf16(Al,  Bl,  acc, 0, 0, 0);
            acc = __builtin_amdgcn_mfma_f32_16x16x32_bf16(Ah,  Bl2, acc, 0, 0, 0);
            acc = __builtin_amdgcn_mfma_f32_16x16x32_bf16(Al2, Bh,  acc, 0, 0, 0);
        }

        // f64 partial merge every 8 chunks (fp32 chains capped at 96 adds)
        if ((c & 7) == 7) {
            acc64[0] += (double)acc.x; acc64[1] += (double)acc.y;
            acc64[2] += (double)acc.z; acc64[3] += (double)acc.w;
            acc = (f32x4){0.f, 0.f, 0.f, 0.f};
        }

        // write chunk c+1 (prefetched last iteration) into the other buffer
        if (c + 1 < NCH) {
            unsigned int h[2], l[2], l2[2];
            cvt4(pf, h, l, l2);
            const int nbuf = (c + 1) & 1;
            *(u32x2*)&SM[nbuf][s_tt][s_ks][0][s_off] = *(u32x2*)h;
            *(u32x2*)&SM[nbuf][s_tt][s_ks][1][s_off] = *(u32x2*)l;
            *(u32x2*)&SM[nbuf][s_tt][s_ks][2][s_off] = *(u32x2*)l2;
        }
        pf = nx;
        __syncthreads();
    }

    // ---- exchange logits (f64) through LDS (aliases SM; 16.9 KB <= 24 KB) ----
    double* lg = (double*)&SM[0][0][0][0][0];   // [32 tok][66] doubles
#pragma unroll
    for (int r = 0; r < 4; ++r) {
        const int t = tt * 16 + (lane >> 4) * 4 + r;      // C/D row = token
        const int e = et * 16 + (lane & 15);              // C/D col = expert
        lg[(size_t)t * 66 + e] = acc64[r];
    }
    __syncthreads();

    const double bias = (double)b[lane];

    // epilogue (R5-verified): wave wv handles tokens [wv*4, wv*4+4)
#pragma unroll 1
    for (int i = 0; i < 4; ++i) {
        const int t = wv * 4 + i;
        const int token = tok0 + t;
        const double v = lg[(size_t)t * 66 + lane] + bias;

        // argmax #1 (value desc, tie -> lower lane)
        double bestv = v;
        int besti = lane;
#pragma unroll
        for (int off = 32; off > 0; off >>= 1) {
            double ov = __shfl_xor(bestv, off, 64);
            int oi = __shfl_xor(besti, off, 64);
            if (ov > bestv || (ov == bestv && oi < besti)) { bestv = ov; besti = oi; }
        }

        // argmax #2 excluding winner
        double v2 = (lane == besti) ? -INFINITY : v;
        double best2v = v2;
        int best2i = lane;
#pragma unroll
        for (int off = 32; off > 0; off >>= 1) {
            double ov = __shfl_xor(best2v, off, 64);
            int oi = __shfl_xor(best2i, off, 64);
            if (ov > best2v || (ov == best2v && oi < best2i)) { best2v = ov; best2i = oi; }
        }

        // 2-element softmax; all other experts exactly 0
        const float e2 = expf((float)(best2v - bestv));
        const float denom = 1.0f + e2;
        const float p1v = 1.0f / denom;
        const float p2v = e2 / denom;

        if (token < total_tokens) {
            float outv = 0.0f;
            if (lane == besti) outv = p1v;
            else if (lane == best2i) outv = p2v;
            out_router[(size_t)token * RE + lane] = outv;
            if (lane == 0) {
                out_idx[(size_t)token * 2 + 0] = (float)besti;
                out_idx[(size_t)token * 2 + 1] = (float)best2i;
            }
        }
    }
}

extern "C" void kernel_launch(void* const* d_in, const int* in_sizes, int n_in,
                              void* d_out, int out_size, void* d_ws, size_t ws_size,
                              hipStream_t stream) {
    const float* x = (const float*)d_in[0];
    const float* W = (const float*)d_in[1];
    const float* b = (const float*)d_in[2];

    const int E = in_sizes[2];                 // 64
    const int D = in_sizes[1] / E;             // 2048
    const int T = in_sizes[0] / D;             // 16384
    (void)E; (void)D;

    unsigned int* WB = (unsigned int*)d_ws;    // 64*4*3*1024 B = 768 KB
    float* out_router = (float*)d_out;
    float* out_idx = out_router + (size_t)T * RE;

    wprep_kernel<<<64, 256, 0, stream>>>(W, WB);

    const int grid = (T + TB - 1) / TB;        // 512
    topk_router_kernel<<<grid, 512, 0, stream>>>(x, WB, b, out_router, out_idx, T);
}

// Round 12
// 55.192 us; speedup vs baseline: 65.9934x; 1.1886x over previous
//
#include <hip/hip_runtime.h>
#include <math.h>

// TopK router via MFMA: logits = x @ W^T + b ; top-2 over E=64 ; sparse softmax.
// x: [T=16384, D=2048] f32, W: [64, 2048] f32, b: [64] f32.
// d_out: [T*64] router probs f32, then [T*2] top-k indices as f32.
//
// R12 = R11 (65.6 us, absmax 0.0) occupancy/convoy fix. R11: grid 512,
// 2 blocks/CU, barrier-per-chunk convoy with all pipes < 40%. Now:
// TB=16, grid 1024, 8 waves = (khalf x 4 etiles), LDS 24 KB ->
// 4 blocks/CU = 32 waves/CU; barriers halve to 16/block; 4 independent
// blocks interleave at barriers. Per-CU traffic unchanged.
// Numerics: fp32 MFMA chains bit-identical to R11 (same 96-accumulate
// merge groups m0..m3, same order); only final f64 association changes
// ((m0+m1)+(m2+m3)) -- diff ~1e-16. VGPR must stay <=64 (R11: 28).
// Spill sentinel: WRITE_SIZE ~5 MB.

#define RD 2048
#define RE 64
#define TB 16                    // tokens per block
#define NST 16                   // pipeline steps (each: 64 k per khalf)

typedef __attribute__((ext_vector_type(8))) short bf16x8;
typedef __attribute__((ext_vector_type(4))) float f32x4;
typedef __attribute__((ext_vector_type(4))) unsigned int u32x4;
typedef __attribute__((ext_vector_type(2))) unsigned int u32x2;

__device__ __forceinline__ unsigned short f2b(float f) {  // RNE f32->bf16 bits
    unsigned int u = __float_as_uint(f);
    unsigned int r = ((u >> 16) & 1u) + 0x7fffu;
    return (unsigned short)((u + r) >> 16);
}
__device__ __forceinline__ float b2f(unsigned short h) {
    return __uint_as_float(((unsigned int)h) << 16);
}

// bank-quad XOR swizzle (dword units); involution, preserves 16B alignment
__device__ __forceinline__ int swz(int f) {
    return (f << 2) ^ (((f >> 3) & 7) << 2);
}

// split 8 floats -> packed bf16 h/l/l2 (4 dwords each) -- wprep only
__device__ __forceinline__ void cvt8(const f32x4 a, const f32x4 bq,
                                     unsigned int* h, unsigned int* l,
                                     unsigned int* l2) {
    float v[8] = {a.x, a.y, a.z, a.w, bq.x, bq.y, bq.z, bq.w};
#pragma unroll
    for (int j = 0; j < 4; ++j) {
        const float a0 = v[2 * j], a1 = v[2 * j + 1];
        const unsigned short h0 = f2b(a0); const float r0 = a0 - b2f(h0);
        const unsigned short h1 = f2b(a1); const float r1 = a1 - b2f(h1);
        const unsigned short m0 = f2b(r0); const float s0 = r0 - b2f(m0);
        const unsigned short m1 = f2b(r1); const float s1 = r1 - b2f(m1);
        const unsigned short q0 = f2b(s0);
        const unsigned short q1 = f2b(s1);
        h[j]  = (unsigned int)h0 | ((unsigned int)h1 << 16);
        l[j]  = (unsigned int)m0 | ((unsigned int)m1 << 16);
        l2[j] = (unsigned int)q0 | ((unsigned int)q1 << 16);
    }
}

// split 4 floats -> packed bf16 h/l/l2 (2 dwords each); same pairing as cvt8
__device__ __forceinline__ void cvt4(const f32x4 a,
                                     unsigned int* h, unsigned int* l,
                                     unsigned int* l2) {
    float v[4] = {a.x, a.y, a.z, a.w};
#pragma unroll
    for (int j = 0; j < 2; ++j) {
        const float a0 = v[2 * j], a1 = v[2 * j + 1];
        const unsigned short h0 = f2b(a0); const float r0 = a0 - b2f(h0);
        const unsigned short h1 = f2b(a1); const float r1 = a1 - b2f(h1);
        const unsigned short m0 = f2b(r0); const float s0 = r0 - b2f(m0);
        const unsigned short m1 = f2b(r1); const float s1 = r1 - b2f(m1);
        const unsigned short q0 = f2b(s0);
        const unsigned short q1 = f2b(s1);
        h[j]  = (unsigned int)h0 | ((unsigned int)h1 << 16);
        l[j]  = (unsigned int)m0 | ((unsigned int)m1 << 16);
        l2[j] = (unsigned int)q0 | ((unsigned int)q1 << 16);
    }
}

// ---------- prep: W -> 3-way bf16 B-fragments (identical to R10/R11) ----------
// WB dword layout: ((ks*4 + et)*3 + comp)*256 + lane*4   (64 ks total)
__global__ __launch_bounds__(256) void wprep_kernel(
    const float* __restrict__ W, unsigned int* __restrict__ WB)
{
    const int ks = blockIdx.x;            // 0..63
    const int et = threadIdx.x >> 6;      // 0..3
    const int lane = threadIdx.x & 63;
    const int e = et * 16 + (lane & 15);
    const int k0 = ks * 32 + (lane >> 4) * 8;
    const float* src = W + (size_t)e * RD + k0;
    const f32x4 a = *(const f32x4*)(src);
    const f32x4 bq = *(const f32x4*)(src + 4);
    unsigned int h[4], l[4], l2[4];
    cvt8(a, bq, h, l, l2);
    unsigned int* dst = WB + (size_t)((ks * 4 + et) * 3) * 256 + lane * 4;
    *(u32x4*)(dst)       = *(u32x4*)h;
    *(u32x4*)(dst + 256) = *(u32x4*)l;
    *(u32x4*)(dst + 512) = *(u32x4*)l2;
}

// ---------- main ----------
__global__ __launch_bounds__(512, 4) void topk_router_kernel(
    const float* __restrict__ x,
    const unsigned int* __restrict__ WB,
    const float* __restrict__ b,
    float* __restrict__ out_router,
    float* __restrict__ out_idx,
    int total_tokens)
{
    const int tid = threadIdx.x;
    const int lane = tid & 63;
    const int wv = __builtin_amdgcn_readfirstlane(tid >> 6);  // 0..7
    const int kh = wv >> 2;               // k-half 0..1
    const int et = wv & 3;                // etile 0..3
    const int tok0 = blockIdx.x * TB;

    // SM[buf][kh][ks][comp][256 dwords] = 24 KB -> 4 blocks/CU.
    // Later aliased as lg[2][16][66] f64 (16.9 KB).
    __shared__ __align__(16) unsigned int SM[2][2][2][3][256];

    // staging map: waves 0-3 stage kh0, waves 4-7 stage kh1;
    // thread -> (token, 4 consecutive k); 1 f32x4 per step.
    const int s_kh = tid >> 8;            // 0..1
    const int stok = (tid >> 4) & 15;     // 0..15
    const int part = tid & 15;            // k-quad within 64-k step
    const int tmax = total_tokens - 1;
    const float* gsrc = x + (size_t)min(tok0 + stok, tmax) * RD
                          + s_kh * 1024 + part * 4;
    const int s_ks = part >> 3;                            // kstep within step
    const int s_f  = ((part >> 1) & 3) * 16 + stok;        // frag lane
    const int s_off = swz(s_f) + (part & 1) * 2;           // swizzled dwords

    f32x4 acc = {0.f, 0.f, 0.f, 0.f};
    double acc64[4] = {0.0, 0.0, 0.0, 0.0};

    // prologue: stage step 0, prefetch step 1 into regs
    {
        const f32x4 v0 = *(const f32x4*)(gsrc);
        unsigned int h[2], l[2], l2[2];
        cvt4(v0, h, l, l2);
        *(u32x2*)&SM[0][s_kh][s_ks][0][s_off] = *(u32x2*)h;
        *(u32x2*)&SM[0][s_kh][s_ks][1][s_off] = *(u32x2*)l;
        *(u32x2*)&SM[0][s_kh][s_ks][2][s_off] = *(u32x2*)l2;
    }
    f32x4 pf = *(const f32x4*)(gsrc + 64);
    __syncthreads();

#pragma unroll 1
    for (int s = 0; s < NST; ++s) {
        const int buf = s & 1;
        // issue step s+2's load early (2-deep pipeline)
        const int cn = (s + 2 < NST) ? (s + 2) : 0;
        const f32x4 nx = *(const f32x4*)(gsrc + (size_t)cn * 64);

        // compute step s: 2 ksteps x 6 products (this wave's kh, et)
#pragma unroll
        for (int ks = 0; ks < 2; ++ks) {
            const bf16x8 Ah  = *(const bf16x8*)&SM[buf][kh][ks][0][swz(lane)];
            const bf16x8 Al  = *(const bf16x8*)&SM[buf][kh][ks][1][swz(lane)];
            const bf16x8 Al2 = *(const bf16x8*)&SM[buf][kh][ks][2][swz(lane)];
            const int ksg = kh * 32 + s * 2 + ks;
            const unsigned int* wp =
                WB + (size_t)((ksg * 4 + et) * 3) * 256 + lane * 4;
            const bf16x8 Bh  = *(const bf16x8*)(wp);
            const bf16x8 Bl  = *(const bf16x8*)(wp + 256);
            const bf16x8 Bl2 = *(const bf16x8*)(wp + 512);
            acc = __builtin_amdgcn_mfma_f32_16x16x32_bf16(Ah,  Bh,  acc, 0, 0, 0);
            acc = __builtin_amdgcn_mfma_f32_16x16x32_bf16(Ah,  Bl,  acc, 0, 0, 0);
            acc = __builtin_amdgcn_mfma_f32_16x16x32_bf16(Al,  Bh,  acc, 0, 0, 0);
            acc = __builtin_amdgcn_mfma_f32_16x16x32_bf16(Al,  Bl,  acc, 0, 0, 0);
            acc = __builtin_amdgcn_mfma_f32_16x16x32_bf16(Ah,  Bl2, acc, 0, 0, 0);
            acc = __builtin_amdgcn_mfma_f32_16x16x32_bf16(Al2, Bh,  acc, 0, 0, 0);
        }

        // f64 partial merge every 8 steps (fp32 chains = 96 accumulates,
        // merge boundaries = global chunks 8/16/24 -> bit-identical to R11)
        if ((s & 7) == 7) {
            acc64[0] += (double)acc.x; acc64[1] += (double)acc.y;
            acc64[2] += (double)acc.z; acc64[3] += (double)acc.w;
            acc = (f32x4){0.f, 0.f, 0.f, 0.f};
        }

        // write step s+1 (prefetched last iteration) into the other buffer
        if (s + 1 < NST) {
            unsigned int h[2], l[2], l2[2];
            cvt4(pf, h, l, l2);
            const int nbuf = (s + 1) & 1;
            *(u32x2*)&SM[nbuf][s_kh][s_ks][0][s_off] = *(u32x2*)h;
            *(u32x2*)&SM[nbuf][s_kh][s_ks][1][s_off] = *(u32x2*)l;
            *(u32x2*)&SM[nbuf][s_kh][s_ks][2][s_off] = *(u32x2*)l2;
        }
        pf = nx;
        __syncthreads();
    }

    // ---- exchange logits (f64) through LDS (aliases SM; 16.9 KB <= 24 KB) ----
    double* lg = (double*)&SM[0][0][0][0][0];   // [2 kh][16 tok][66]
#pragma unroll
    for (int r = 0; r < 4; ++r) {
        const int t = (lane >> 4) * 4 + r;                // C/D row = token
        const int e = et * 16 + (lane & 15);              // C/D col = expert
        lg[(size_t)(kh * TB + t) * 66 + e] = acc64[r];
    }
    __syncthreads();

    const double bias = (double)b[lane];

    // epilogue (R5-verified): wave wv handles tokens [wv*2, wv*2+2)
#pragma unroll 1
    for (int i = 0; i < 2; ++i) {
        const int t = wv * 2 + i;
        const int token = tok0 + t;
        const double v = lg[(size_t)t * 66 + lane]
                       + lg[(size_t)(TB + t) * 66 + lane] + bias;

        // argmax #1 (value desc, tie -> lower lane)
        double bestv = v;
        int besti = lane;
#pragma unroll
        for (int off = 32; off > 0; off >>= 1) {
            double ov = __shfl_xor(bestv, off, 64);
            int oi = __shfl_xor(besti, off, 64);
            if (ov > bestv || (ov == bestv && oi < besti)) { bestv = ov; besti = oi; }
        }

        // argmax #2 excluding winner
        double v2 = (lane == besti) ? -INFINITY : v;
        double best2v = v2;
        int best2i = lane;
#pragma unroll
        for (int off = 32; off > 0; off >>= 1) {
            double ov = __shfl_xor(best2v, off, 64);
            int oi = __shfl_xor(best2i, off, 64);
            if (ov > best2v || (ov == best2v && oi < best2i)) { best2v = ov; best2i = oi; }
        }

        // 2-element softmax; all other experts exactly 0
        const float e2 = expf((float)(best2v - bestv));
        const float denom = 1.0f + e2;
        const float p1v = 1.0f / denom;
        const float p2v = e2 / denom;

        if (token < total_tokens) {
            float outv = 0.0f;
            if (lane == besti) outv = p1v;
            else if (lane == best2i) outv = p2v;
            out_router[(size_t)token * RE + lane] = outv;
            if (lane == 0) {
                out_idx[(size_t)token * 2 + 0] = (float)besti;
                out_idx[(size_t)token * 2 + 1] = (float)best2i;
            }
        }
    }
}

extern "C" void kernel_launch(void* const* d_in, const int* in_sizes, int n_in,
                              void* d_out, int out_size, void* d_ws, size_t ws_size,
                              hipStream_t stream) {
    const float* x = (const float*)d_in[0];
    const float* W = (const float*)d_in[1];
    const float* b = (const float*)d_in[2];

    const int E = in_sizes[2];                 // 64
    const int D = in_sizes[1] / E;             // 2048
    const int T = in_sizes[0] / D;             // 16384
    (void)E; (void)D;

    unsigned int* WB = (unsigned int*)d_ws;    // 64*4*3*1024 B = 768 KB
    float* out_router = (float*)d_out;
    float* out_idx = out_router + (size_t)T * RE;

    wprep_kernel<<<64, 256, 0, stream>>>(W, WB);

    const int grid = (T + TB - 1) / TB;        // 1024
    topk_router_kernel<<<grid, 512, 0, stream>>>(x, WB, b, out_router, out_idx, T);
}

// Round 13
// 54.170 us; speedup vs baseline: 67.2382x; 1.0189x over previous
//
#include <hip/hip_runtime.h>
#include <math.h>

// TopK router via MFMA: logits = x @ W^T + b ; top-2 over E=64 ; sparse softmax.
// x: [T=16384, D=2048] f32, W: [64, 2048] f32, b: [64] f32.
// d_out: [T*64] router probs f32, then [T*2] top-k indices as f32.
//
// R13 = R12 (55.2 us, absmax 0.0) with a smaller barrier domain. R12:
// 512-thr blocks, 4 blocks/CU, all pipes <= 24% -- barrier convoys of
// 8 waves leave gaps. Now: 256-thr blocks (4 waves = 4 etiles, no kh
// split), TB=16, 32 steps, LDS 12 KB -> 8 blocks/CU = 32 waves/CU.
// Barriers convoy only 4 waves; 8 independent block-streams fill the
// gaps. Per-CU traffic unchanged. Numerics identical to R10/R11
// (absmax 0): same 3-way bf16 split, same 6 products, same fragment
// k-convention, f64 merge every 8 chunks, sequential merge order.
// Spill sentinel: WRITE_SIZE ~4.2 MB; VGPR ~32.

#define RD 2048
#define RE 64
#define TB 16                    // tokens per block
#define NCH 32                   // chunks of 64 k

typedef __attribute__((ext_vector_type(8))) short bf16x8;
typedef __attribute__((ext_vector_type(4))) float f32x4;
typedef __attribute__((ext_vector_type(4))) unsigned int u32x4;
typedef __attribute__((ext_vector_type(2))) unsigned int u32x2;

__device__ __forceinline__ unsigned short f2b(float f) {  // RNE f32->bf16 bits
    unsigned int u = __float_as_uint(f);
    unsigned int r = ((u >> 16) & 1u) + 0x7fffu;
    return (unsigned short)((u + r) >> 16);
}
__device__ __forceinline__ float b2f(unsigned short h) {
    return __uint_as_float(((unsigned int)h) << 16);
}

// bank-quad XOR swizzle (dword units); involution, preserves 16B alignment
__device__ __forceinline__ int swz(int f) {
    return (f << 2) ^ (((f >> 3) & 7) << 2);
}

// split 8 floats -> packed bf16 h/l/l2 (4 dwords each) -- wprep only
__device__ __forceinline__ void cvt8(const f32x4 a, const f32x4 bq,
                                     unsigned int* h, unsigned int* l,
                                     unsigned int* l2) {
    float v[8] = {a.x, a.y, a.z, a.w, bq.x, bq.y, bq.z, bq.w};
#pragma unroll
    for (int j = 0; j < 4; ++j) {
        const float a0 = v[2 * j], a1 = v[2 * j + 1];
        const unsigned short h0 = f2b(a0); const float r0 = a0 - b2f(h0);
        const unsigned short h1 = f2b(a1); const float r1 = a1 - b2f(h1);
        const unsigned short m0 = f2b(r0); const float s0 = r0 - b2f(m0);
        const unsigned short m1 = f2b(r1); const float s1 = r1 - b2f(m1);
        const unsigned short q0 = f2b(s0);
        const unsigned short q1 = f2b(s1);
        h[j]  = (unsigned int)h0 | ((unsigned int)h1 << 16);
        l[j]  = (unsigned int)m0 | ((unsigned int)m1 << 16);
        l2[j] = (unsigned int)q0 | ((unsigned int)q1 << 16);
    }
}

// split 4 floats -> packed bf16 h/l/l2 (2 dwords each); same pairing as cvt8
__device__ __forceinline__ void cvt4(const f32x4 a,
                                     unsigned int* h, unsigned int* l,
                                     unsigned int* l2) {
    float v[4] = {a.x, a.y, a.z, a.w};
#pragma unroll
    for (int j = 0; j < 2; ++j) {
        const float a0 = v[2 * j], a1 = v[2 * j + 1];
        const unsigned short h0 = f2b(a0); const float r0 = a0 - b2f(h0);
        const unsigned short h1 = f2b(a1); const float r1 = a1 - b2f(h1);
        const unsigned short m0 = f2b(r0); const float s0 = r0 - b2f(m0);
        const unsigned short m1 = f2b(r1); const float s1 = r1 - b2f(m1);
        const unsigned short q0 = f2b(s0);
        const unsigned short q1 = f2b(s1);
        h[j]  = (unsigned int)h0 | ((unsigned int)h1 << 16);
        l[j]  = (unsigned int)m0 | ((unsigned int)m1 << 16);
        l2[j] = (unsigned int)q0 | ((unsigned int)q1 << 16);
    }
}

// ---------- prep: W -> 3-way bf16 B-fragments (identical to R10-R12) ----------
// WB dword layout: ((ks*4 + et)*3 + comp)*256 + lane*4   (64 ks total)
__global__ __launch_bounds__(256) void wprep_kernel(
    const float* __restrict__ W, unsigned int* __restrict__ WB)
{
    const int ks = blockIdx.x;            // 0..63
    const int et = threadIdx.x >> 6;      // 0..3
    const int lane = threadIdx.x & 63;
    const int e = et * 16 + (lane & 15);
    const int k0 = ks * 32 + (lane >> 4) * 8;
    const float* src = W + (size_t)e * RD + k0;
    const f32x4 a = *(const f32x4*)(src);
    const f32x4 bq = *(const f32x4*)(src + 4);
    unsigned int h[4], l[4], l2[4];
    cvt8(a, bq, h, l, l2);
    unsigned int* dst = WB + (size_t)((ks * 4 + et) * 3) * 256 + lane * 4;
    *(u32x4*)(dst)       = *(u32x4*)h;
    *(u32x4*)(dst + 256) = *(u32x4*)l;
    *(u32x4*)(dst + 512) = *(u32x4*)l2;
}

// ---------- main ----------
__global__ __launch_bounds__(256, 4) void topk_router_kernel(
    const float* __restrict__ x,
    const unsigned int* __restrict__ WB,
    const float* __restrict__ b,
    float* __restrict__ out_router,
    float* __restrict__ out_idx,
    int total_tokens)
{
    const int tid = threadIdx.x;
    const int lane = tid & 63;
    const int et = __builtin_amdgcn_readfirstlane(tid >> 6);  // etile 0..3
    const int tok0 = blockIdx.x * TB;

    // SM[buf][ks][comp][256 dwords] = 12 KB -> 8 blocks/CU.
    // Later aliased as lg[16][66] f64 (8.4 KB).
    __shared__ __align__(16) unsigned int SM[2][2][3][256];

    // staging map: thread -> (token, 4 consecutive k); 1 f32x4 per step
    const int stok = tid >> 4;            // 0..15
    const int part = tid & 15;            // k-quad within 64-k chunk
    const int tmax = total_tokens - 1;
    const float* gsrc = x + (size_t)min(tok0 + stok, tmax) * RD + part * 4;
    const int s_ks = part >> 3;                            // kstep within chunk
    const int s_f  = ((part >> 1) & 3) * 16 + stok;        // frag lane
    const int s_off = swz(s_f) + (part & 1) * 2;           // swizzled dwords

    f32x4 acc = {0.f, 0.f, 0.f, 0.f};
    double acc64[4] = {0.0, 0.0, 0.0, 0.0};

    // prologue: stage chunk 0, prefetch chunk 1 into regs
    {
        const f32x4 v0 = *(const f32x4*)(gsrc);
        unsigned int h[2], l[2], l2[2];
        cvt4(v0, h, l, l2);
        *(u32x2*)&SM[0][s_ks][0][s_off] = *(u32x2*)h;
        *(u32x2*)&SM[0][s_ks][1][s_off] = *(u32x2*)l;
        *(u32x2*)&SM[0][s_ks][2][s_off] = *(u32x2*)l2;
    }
    f32x4 pf = *(const f32x4*)(gsrc + 64);
    __syncthreads();

#pragma unroll 1
    for (int c = 0; c < NCH; ++c) {
        const int buf = c & 1;
        // issue chunk c+2's load early (2-deep pipeline)
        const int cn = (c + 2 < NCH) ? (c + 2) : 0;
        const f32x4 nx = *(const f32x4*)(gsrc + (size_t)cn * 64);

        // compute chunk c: 2 ksteps x 6 products (this wave's etile)
#pragma unroll
        for (int ks = 0; ks < 2; ++ks) {
            const bf16x8 Ah  = *(const bf16x8*)&SM[buf][ks][0][swz(lane)];
            const bf16x8 Al  = *(const bf16x8*)&SM[buf][ks][1][swz(lane)];
            const bf16x8 Al2 = *(const bf16x8*)&SM[buf][ks][2][swz(lane)];
            const int ksg = c * 2 + ks;
            const unsigned int* wp =
                WB + (size_t)((ksg * 4 + et) * 3) * 256 + lane * 4;
            const bf16x8 Bh  = *(const bf16x8*)(wp);
            const bf16x8 Bl  = *(const bf16x8*)(wp + 256);
            const bf16x8 Bl2 = *(const bf16x8*)(wp + 512);
            acc = __builtin_amdgcn_mfma_f32_16x16x32_bf16(Ah,  Bh,  acc, 0, 0, 0);
            acc = __builtin_amdgcn_mfma_f32_16x16x32_bf16(Ah,  Bl,  acc, 0, 0, 0);
            acc = __builtin_amdgcn_mfma_f32_16x16x32_bf16(Al,  Bh,  acc, 0, 0, 0);
            acc = __builtin_amdgcn_mfma_f32_16x16x32_bf16(Al,  Bl,  acc, 0, 0, 0);
            acc = __builtin_amdgcn_mfma_f32_16x16x32_bf16(Ah,  Bl2, acc, 0, 0, 0);
            acc = __builtin_amdgcn_mfma_f32_16x16x32_bf16(Al2, Bh,  acc, 0, 0, 0);
        }

        // f64 partial merge every 8 chunks (fp32 chains = 96 accumulates;
        // boundaries at chunks 8/16/24/32 -- identical to R10/R11)
        if ((c & 7) == 7) {
            acc64[0] += (double)acc.x; acc64[1] += (double)acc.y;
            acc64[2] += (double)acc.z; acc64[3] += (double)acc.w;
            acc = (f32x4){0.f, 0.f, 0.f, 0.f};
        }

        // write chunk c+1 (prefetched last iteration) into the other buffer
        if (c + 1 < NCH) {
            unsigned int h[2], l[2], l2[2];
            cvt4(pf, h, l, l2);
            const int nbuf = (c + 1) & 1;
            *(u32x2*)&SM[nbuf][s_ks][0][s_off] = *(u32x2*)h;
            *(u32x2*)&SM[nbuf][s_ks][1][s_off] = *(u32x2*)l;
            *(u32x2*)&SM[nbuf][s_ks][2][s_off] = *(u32x2*)l2;
        }
        pf = nx;
        __syncthreads();
    }

    // ---- exchange logits (f64) through LDS (aliases SM; 8.4 KB <= 12 KB) ----
    double* lg = (double*)&SM[0][0][0][0];   // [16 tok][66]
#pragma unroll
    for (int r = 0; r < 4; ++r) {
        const int t = (lane >> 4) * 4 + r;                // C/D row = token
        const int e = et * 16 + (lane & 15);              // C/D col = expert
        lg[(size_t)t * 66 + e] = acc64[r];
    }
    __syncthreads();

    const double bias = (double)b[lane];

    // epilogue (R5-verified): wave et handles tokens [et*4, et*4+4)
#pragma unroll 1
    for (int i = 0; i < 4; ++i) {
        const int t = et * 4 + i;
        const int token = tok0 + t;
        const double v = lg[(size_t)t * 66 + lane] + bias;

        // argmax #1 (value desc, tie -> lower lane)
        double bestv = v;
        int besti = lane;
#pragma unroll
        for (int off = 32; off > 0; off >>= 1) {
            double ov = __shfl_xor(bestv, off, 64);
            int oi = __shfl_xor(besti, off, 64);
            if (ov > bestv || (ov == bestv && oi < besti)) { bestv = ov; besti = oi; }
        }

        // argmax #2 excluding winner
        double v2 = (lane == besti) ? -INFINITY : v;
        double best2v = v2;
        int best2i = lane;
#pragma unroll
        for (int off = 32; off > 0; off >>= 1) {
            double ov = __shfl_xor(best2v, off, 64);
            int oi = __shfl_xor(best2i, off, 64);
            if (ov > best2v || (ov == best2v && oi < best2i)) { best2v = ov; best2i = oi; }
        }

        // 2-element softmax; all other experts exactly 0
        const float e2 = expf((float)(best2v - bestv));
        const float denom = 1.0f + e2;
        const float p1v = 1.0f / denom;
        const float p2v = e2 / denom;

        if (token < total_tokens) {
            float outv = 0.0f;
            if (lane == besti) outv = p1v;
            else if (lane == best2i) outv = p2v;
            out_router[(size_t)token * RE + lane] = outv;
            if (lane == 0) {
                out_idx[(size_t)token * 2 + 0] = (float)besti;
                out_idx[(size_t)token * 2 + 1] = (float)best2i;
            }
        }
    }
}

extern "C" void kernel_launch(void* const* d_in, const int* in_sizes, int n_in,
                              void* d_out, int out_size, void* d_ws, size_t ws_size,
                              hipStream_t stream) {
    const float* x = (const float*)d_in[0];
    const float* W = (const float*)d_in[1];
    const float* b = (const float*)d_in[2];

    const int E = in_sizes[2];                 // 64
    const int D = in_sizes[1] / E;             // 2048
    const int T = in_sizes[0] / D;             // 16384
    (void)E; (void)D;

    unsigned int* WB = (unsigned int*)d_ws;    // 64*4*3*1024 B = 768 KB
    float* out_router = (float*)d_out;
    float* out_idx = out_router + (size_t)T * RE;

    wprep_kernel<<<64, 256, 0, stream>>>(W, WB);

    const int grid = (T + TB - 1) / TB;        // 1024
    topk_router_kernel<<<grid, 256, 0, stream>>>(x, WB, b, out_router, out_idx, T);
}